// Round 1
// baseline (535.997 us; speedup 1.0000x reference)
//
#include <hip/hip_runtime.h>

#define Nn 2048
#define Bb 16
#define Dd 8
#define BN (Bb * Nn)       // 32768
#define NN ((size_t)Nn * Nn)
#define EC 4               // e-rows per chunk
#define ECH (Nn / EC)      // 512 e-chunks

#define XW_BYTES   ((size_t)Nn * Bb * Dd * 4)          // 1 MB
#define PART_BYTES ((size_t)ECH * BN * 4)              // 67 MB
#define RCG 8                                          // reduce chunk-groups

typedef float v4f __attribute__((ext_vector_type(4)));
typedef float v2f __attribute__((ext_vector_type(2)));

// Prep: zero the output accumulator and build xw[e][b][d] = Xd*(Wshort+1).
__global__ void prep_kernel(const float* __restrict__ Xd,
                            const float* __restrict__ Wshort,
                            float* __restrict__ xw,
                            float* __restrict__ out) {
    int t = blockIdx.x * blockDim.x + threadIdx.x;   // t in [0, BN)
    if (t >= BN) return;
    out[t] = 0.0f;
    int b = t >> 11;            // t / N
    int e = t & (Nn - 1);       // t % N
    float v[Dd];
#pragma unroll
    for (int d = 0; d < Dd; ++d) {
        int idx = d * BN + b * Nn + e;               // coalesced over e
        v[d] = Xd[idx] * (Wshort[idx] + 1.0f);
    }
    v4f* dst = (v4f*)(xw + (size_t)e * (Bb * Dd) + b * Dd);  // 32B aligned
    dst[0] = (v4f){v[0], v[1], v[2], v[3]};
    dst[1] = (v4f){v[4], v[5], v[6], v[7]};
}

// Main: each thread owns 2 consecutive o's for all 16 b's over EC e-rows.
// Key change vs prior version: o-tile halved (acc 64->32 VGPRs), ALL loads
// for an e-iteration issued before any consumption (26 in-flight loads/wave
// ~= 13 KB outstanding), xw broadcast values staged in LDS instead of
// per-b scalar loads on the critical path.
template <bool USE_PART>
__global__ __launch_bounds__(256) void main_kernel(
        const float* __restrict__ W,
        const float* __restrict__ Wlong,
        const float* __restrict__ delaymap,
        const float* __restrict__ frac,
        const float* __restrict__ signs_pre,
        const float* __restrict__ xw,
        float* __restrict__ partial,
        float* __restrict__ out) {
    const int o = (blockIdx.x * 256 + threadIdx.x) * 2;   // 2 consecutive o's
    const int chunk = blockIdx.y;
    const int e0 = chunk * EC;

    // Stage xw[e0..e0+EC)[b][d] (512 floats = 2 KB) into LDS once.
    __shared__ float sxw[EC * Bb * Dd];
    {
        const v2f* src = (const v2f*)(xw + (size_t)e0 * (Bb * Dd));
        ((v2f*)sxw)[threadIdx.x] = src[threadIdx.x];
    }
    __syncthreads();

    v2f acc[Bb];
#pragma unroll
    for (int b = 0; b < Bb; ++b) acc[b] = (v2f)0.0f;

#pragma unroll 1
    for (int ei = 0; ei < EC; ++ei) {
        const int e = e0 + ei;
        const size_t eo = (size_t)e * Nn + o;

        // ---- issue ALL loads for this e before consuming anything ----
        const v2f w  = *(const v2f*)(W + eo);
        const v2f fr = *(const v2f*)(frac + eo);

        v2f dm[Dd];
#pragma unroll
        for (int d = 0; d < Dd; ++d)
            dm[d] = *(const v2f*)(delaymap + (size_t)d * NN + eo);

        v2f wl[Bb];
#pragma unroll
        for (int b = 0; b < Bb; ++b)
            wl[b] = *(const v2f*)(Wlong + (size_t)b * NN + eo);

        const float sp = signs_pre[e];
        const float sgn = (sp > 0.0f) ? 1.0f : ((sp < 0.0f) ? -1.0f : 0.0f);

        v2f sg, base;
#pragma unroll
        for (int c = 0; c < 2; ++c) {
            sg[c]   = (w[c] > 0.0f) ? sgn : 0.0f;
            base[c] = w[c] * (1.0f - fr[c]);
        }

        const float* xwe = sxw + ei * (Bb * Dd);   // LDS broadcast reads

#pragma unroll
        for (int b = 0; b < Bb; ++b) {
            v2f inner = dm[0] * xwe[b * Dd + 0];
#pragma unroll
            for (int d = 1; d < Dd; ++d)
                inner += dm[d] * xwe[b * Dd + d];
            const v2f weff = sg * (base + wl[b] * fr);
            acc[b] += weff * inner;
        }
    }

    if (USE_PART) {
        float* pbase = partial + (size_t)chunk * BN + o;
#pragma unroll
        for (int b = 0; b < Bb; ++b)
            *(v2f*)(pbase + b * Nn) = acc[b];
    } else {
#pragma unroll
        for (int b = 0; b < Bb; ++b) {
            float* op = out + b * Nn + o;
            atomicAdd(op + 0, acc[b][0]);
            atomicAdd(op + 1, acc[b][1]);
        }
    }
}

// Reduce: out[t] += sum over a 64-chunk group of partial[c][t].
__global__ __launch_bounds__(256) void reduce_kernel(
        const float* __restrict__ partial, float* __restrict__ out) {
    const int t = blockIdx.x * 256 + threadIdx.x;   // [0, BN)
    const int cg = blockIdx.y;                      // [0, RCG)
    const int c0 = cg * (ECH / RCG);
    float s0 = 0.f, s1 = 0.f, s2 = 0.f, s3 = 0.f;
#pragma unroll 4
    for (int c = c0; c < c0 + (ECH / RCG); c += 4) {
        s0 += partial[(size_t)(c + 0) * BN + t];
        s1 += partial[(size_t)(c + 1) * BN + t];
        s2 += partial[(size_t)(c + 2) * BN + t];
        s3 += partial[(size_t)(c + 3) * BN + t];
    }
    atomicAdd(out + t, (s0 + s1) + (s2 + s3));
}

extern "C" void kernel_launch(void* const* d_in, const int* in_sizes, int n_in,
                              void* d_out, int out_size, void* d_ws, size_t ws_size,
                              hipStream_t stream) {
    const float* W         = (const float*)d_in[0];
    const float* Wlong     = (const float*)d_in[1];
    const float* Wshort    = (const float*)d_in[2];
    const float* Xd        = (const float*)d_in[3];
    const float* delaymap  = (const float*)d_in[4];
    const float* frac      = (const float*)d_in[5];
    const float* signs_pre = (const float*)d_in[6];
    float* out = (float*)d_out;
    float* xw  = (float*)d_ws;                       // 1 MB
    float* partial = (float*)((char*)d_ws + XW_BYTES);

    prep_kernel<<<BN / 256, 256, 0, stream>>>(Xd, Wshort, xw, out);

    dim3 grid(Nn / (256 * 2), ECH);   // 4 x 512 = 2048 blocks
    if (ws_size >= XW_BYTES + PART_BYTES) {
        main_kernel<true><<<grid, 256, 0, stream>>>(W, Wlong, delaymap, frac,
                                                    signs_pre, xw, partial, out);
        dim3 rgrid(BN / 256, RCG);    // 128 x 8 = 1024 blocks
        reduce_kernel<<<rgrid, 256, 0, stream>>>(partial, out);
    } else {
        main_kernel<false><<<grid, 256, 0, stream>>>(W, Wlong, delaymap, frac,
                                                     signs_pre, xw, partial, out);
    }
}

// Round 2
// 480.052 us; speedup vs baseline: 1.1165x; 1.1165x over previous
//
#include <hip/hip_runtime.h>

#define Nn 2048
#define Bb 16
#define Dd 8
#define BN (Bb * Nn)       // 32768
#define NN ((size_t)Nn * Nn)
#define EC 8               // e-rows per chunk
#define ECH (Nn / EC)      // 256 e-chunks

#define XW_BYTES   ((size_t)Nn * Bb * Dd * 4)          // 1 MB
#define PART_BYTES ((size_t)ECH * BN * 4)              // 33.5 MB
#define RCG 8                                          // reduce chunk-groups

typedef float v4f __attribute__((ext_vector_type(4)));

// Prep: zero the output accumulator and build xw[e][b][d] = Xd*(Wshort+1).
__global__ void prep_kernel(const float* __restrict__ Xd,
                            const float* __restrict__ Wshort,
                            float* __restrict__ xw,
                            float* __restrict__ out) {
    int t = blockIdx.x * blockDim.x + threadIdx.x;   // t in [0, BN)
    if (t >= BN) return;
    out[t] = 0.0f;
    int b = t >> 11;            // t / N
    int e = t & (Nn - 1);       // t % N
    float v[Dd];
#pragma unroll
    for (int d = 0; d < Dd; ++d) {
        int idx = d * BN + b * Nn + e;               // coalesced over e
        v[d] = Xd[idx] * (Wshort[idx] + 1.0f);
    }
    v4f* dst = (v4f*)(xw + (size_t)e * (Bb * Dd) + b * Dd);  // 32B aligned
    dst[0] = (v4f){v[0], v[1], v[2], v[3]};
    dst[1] = (v4f){v[4], v[5], v[6], v[7]};
}

// Main: each thread owns 4 consecutive o's for all 16 b's over EC e-rows.
// Round-2 design: __launch_bounds__(256,2) grants VGPR budget (~256 cap) so
// the compiler can keep loads in flight; wl loads batched 4-at-a-time
// (4 KB outstanding per wave in the b-loop) on top of the 10-load
// w/fr/dm prologue. EC=8 -> 512 blocks = exactly 2 blocks/CU, and halves
// partial traffic vs EC=4.
template <bool USE_PART>
__global__ __launch_bounds__(256, 2) void main_kernel(
        const float* __restrict__ W,
        const float* __restrict__ Wlong,
        const float* __restrict__ delaymap,
        const float* __restrict__ frac,
        const float* __restrict__ signs_pre,
        const float* __restrict__ xw,
        float* __restrict__ partial,
        float* __restrict__ out) {
    const int o = (blockIdx.x * 256 + threadIdx.x) * 4;   // 4 consecutive o's
    const int chunk = blockIdx.y;
    const int e0 = chunk * EC;

    // Stage xw[e0..e0+EC)[b][d] (1024 floats = 4 KB) into LDS once.
    __shared__ float sxw[EC * Bb * Dd];
    {
        const v4f* src = (const v4f*)(xw + (size_t)e0 * (Bb * Dd));
        ((v4f*)sxw)[threadIdx.x] = src[threadIdx.x];   // 256 * 16B = 4 KB
    }
    __syncthreads();

    v4f acc[Bb];
#pragma unroll
    for (int b = 0; b < Bb; ++b) acc[b] = (v4f)0.0f;

#pragma unroll 1
    for (int ei = 0; ei < EC; ++ei) {
        const int e = e0 + ei;
        const size_t eo = (size_t)e * Nn + o;

        // prologue loads for this e: 10 x dwordx4 (w, fr, dm[0..7])
        const v4f w  = *(const v4f*)(W + eo);
        const v4f fr = *(const v4f*)(frac + eo);
        v4f dm[Dd];
#pragma unroll
        for (int d = 0; d < Dd; ++d)
            dm[d] = *(const v4f*)(delaymap + (size_t)d * NN + eo);

        const float sp = signs_pre[e];
        const float sgn = (sp > 0.0f) ? 1.0f : ((sp < 0.0f) ? -1.0f : 0.0f);

        v4f sg, base;
#pragma unroll
        for (int c = 0; c < 4; ++c) {
            sg[c]   = (w[c] > 0.0f) ? sgn : 0.0f;
            base[c] = w[c] * (1.0f - fr[c]);
        }

        const float* xwe = sxw + ei * (Bb * Dd);   // LDS broadcast reads

        // b-loop in groups of 4: 4 x dwordx4 wl loads in flight, then compute.
#pragma unroll
        for (int bg = 0; bg < Bb; bg += 4) {
            const v4f wl0 = *(const v4f*)(Wlong + (size_t)(bg + 0) * NN + eo);
            const v4f wl1 = *(const v4f*)(Wlong + (size_t)(bg + 1) * NN + eo);
            const v4f wl2 = *(const v4f*)(Wlong + (size_t)(bg + 2) * NN + eo);
            const v4f wl3 = *(const v4f*)(Wlong + (size_t)(bg + 3) * NN + eo);

            v4f in0 = dm[0] * xwe[(bg + 0) * Dd + 0];
            v4f in1 = dm[0] * xwe[(bg + 1) * Dd + 0];
            v4f in2 = dm[0] * xwe[(bg + 2) * Dd + 0];
            v4f in3 = dm[0] * xwe[(bg + 3) * Dd + 0];
#pragma unroll
            for (int d = 1; d < Dd; ++d) {
                in0 += dm[d] * xwe[(bg + 0) * Dd + d];
                in1 += dm[d] * xwe[(bg + 1) * Dd + d];
                in2 += dm[d] * xwe[(bg + 2) * Dd + d];
                in3 += dm[d] * xwe[(bg + 3) * Dd + d];
            }
            acc[bg + 0] += sg * (base + wl0 * fr) * in0;
            acc[bg + 1] += sg * (base + wl1 * fr) * in1;
            acc[bg + 2] += sg * (base + wl2 * fr) * in2;
            acc[bg + 3] += sg * (base + wl3 * fr) * in3;
        }
    }

    if (USE_PART) {
        float* pbase = partial + (size_t)chunk * BN + o;
#pragma unroll
        for (int b = 0; b < Bb; ++b)
            *(v4f*)(pbase + b * Nn) = acc[b];
    } else {
#pragma unroll
        for (int b = 0; b < Bb; ++b) {
            float* op = out + b * Nn + o;
            atomicAdd(op + 0, acc[b][0]);
            atomicAdd(op + 1, acc[b][1]);
            atomicAdd(op + 2, acc[b][2]);
            atomicAdd(op + 3, acc[b][3]);
        }
    }
}

// Reduce: out[t] += sum over a 32-chunk group of partial[c][t].
__global__ __launch_bounds__(256) void reduce_kernel(
        const float* __restrict__ partial, float* __restrict__ out) {
    const int t = blockIdx.x * 256 + threadIdx.x;   // [0, BN)
    const int cg = blockIdx.y;                      // [0, RCG)
    const int c0 = cg * (ECH / RCG);
    float s0 = 0.f, s1 = 0.f, s2 = 0.f, s3 = 0.f;
#pragma unroll 4
    for (int c = c0; c < c0 + (ECH / RCG); c += 4) {
        s0 += partial[(size_t)(c + 0) * BN + t];
        s1 += partial[(size_t)(c + 1) * BN + t];
        s2 += partial[(size_t)(c + 2) * BN + t];
        s3 += partial[(size_t)(c + 3) * BN + t];
    }
    atomicAdd(out + t, (s0 + s1) + (s2 + s3));
}

extern "C" void kernel_launch(void* const* d_in, const int* in_sizes, int n_in,
                              void* d_out, int out_size, void* d_ws, size_t ws_size,
                              hipStream_t stream) {
    const float* W         = (const float*)d_in[0];
    const float* Wlong     = (const float*)d_in[1];
    const float* Wshort    = (const float*)d_in[2];
    const float* Xd        = (const float*)d_in[3];
    const float* delaymap  = (const float*)d_in[4];
    const float* frac      = (const float*)d_in[5];
    const float* signs_pre = (const float*)d_in[6];
    float* out = (float*)d_out;
    float* xw  = (float*)d_ws;                       // 1 MB
    float* partial = (float*)((char*)d_ws + XW_BYTES);

    prep_kernel<<<BN / 256, 256, 0, stream>>>(Xd, Wshort, xw, out);

    dim3 grid(Nn / (256 * 4), ECH);   // 2 x 256 = 512 blocks, 2 per CU
    if (ws_size >= XW_BYTES + PART_BYTES) {
        main_kernel<true><<<grid, 256, 0, stream>>>(W, Wlong, delaymap, frac,
                                                    signs_pre, xw, partial, out);
        dim3 rgrid(BN / 256, RCG);    // 128 x 8 = 1024 blocks
        reduce_kernel<<<rgrid, 256, 0, stream>>>(partial, out);
    } else {
        main_kernel<false><<<grid, 256, 0, stream>>>(W, Wlong, delaymap, frac,
                                                     signs_pre, xw, partial, out);
    }
}